// Round 3
// baseline (27.749 us; speedup 1.0000x reference)
//
#include <hip/hip_runtime.h>

// ColorReducer: per-pixel argmin_k of d2 = (x2 - 2.0f*cross) + p2 with the
// EXACT R0 expression tree (bit-exact vs numpy reference, absmax 0.0 verified):
//   cross = ((r*pr + g*pg) + b*pb), x2 = ((r*r + g*g) + b*b),
//   d2 = (x2 - 2.0f*cross) + p2, +inf seed, strict < (np.argmin tie-break).
// R2 = R0 math + structural pipelining ONLY (R1 bundled numeric rewrites and
// nontemporal stores with the structure change and failed; this isolates):
//  - 8 px/thread, all 6 float4 loads issued up front (batch-1 loads fly under
//    batch-0 compute; one k-loop over all 8 pixels for max ILP).
//  - grid = 8192 waves = 1 resident generation at 8 waves/SIMD.
//  - plain float4 stores (no nt).

constexpr int HW    = 512 * 512;   // 2^18
constexpr int KCOL  = 16;
constexpr long NPIX = 16L * HW;    // 4,194,304
constexpr int PPT   = 8;           // pixels per thread

__global__ __launch_bounds__(256) void color_reduce_kernel(
    const float* __restrict__ x,       // (B, 3, H, W)
    const float* __restrict__ pal,     // (16, 3)
    float* __restrict__ out)           // (B, 3, H, W)
{
    __shared__ float spal[KCOL * 3];
    if (threadIdx.x < KCOL * 3) spal[threadIdx.x] = pal[threadIdx.x];
    __syncthreads();

    const long t  = (long)blockIdx.x * blockDim.x + threadIdx.x;
    const long n0 = t * PPT;
    const int b   = (int)(n0 >> 18);        // n0 / HW
    const int pix = (int)(n0 & (HW - 1));   // n0 % HW

    const float* base = x + (size_t)b * 3 * HW + pix;

    // All 6 loads issued up front — memory latency hides under compute.
    const float4 rv0 = *reinterpret_cast<const float4*>(base);
    const float4 rv1 = *reinterpret_cast<const float4*>(base + 4);
    const float4 gv0 = *reinterpret_cast<const float4*>(base + HW);
    const float4 gv1 = *reinterpret_cast<const float4*>(base + HW + 4);
    const float4 bv0 = *reinterpret_cast<const float4*>(base + 2 * HW);
    const float4 bv1 = *reinterpret_cast<const float4*>(base + 2 * HW + 4);

    float r[8]  = {rv0.x, rv0.y, rv0.z, rv0.w, rv1.x, rv1.y, rv1.z, rv1.w};
    float g[8]  = {gv0.x, gv0.y, gv0.z, gv0.w, gv1.x, gv1.y, gv1.z, gv1.w};
    float bl[8] = {bv0.x, bv0.y, bv0.z, bv0.w, bv1.x, bv1.y, bv1.z, bv1.w};

    float x2[8], best[8];
    int bestk[8];
#pragma unroll
    for (int i = 0; i < 8; ++i) {
        x2[i] = __fadd_rn(__fadd_rn(__fmul_rn(r[i], r[i]),
                                    __fmul_rn(g[i], g[i])),
                          __fmul_rn(bl[i], bl[i]));
        best[i]  = 3.4e38f;
        bestk[i] = 0;
    }

#pragma unroll
    for (int k = 0; k < KCOL; ++k) {
        const float pr = pal[3 * k + 0];   // uniform -> s_load/SGPR
        const float pg = pal[3 * k + 1];
        const float pb = pal[3 * k + 2];
        const float p2 = __fadd_rn(__fadd_rn(__fmul_rn(pr, pr),
                                             __fmul_rn(pg, pg)),
                                   __fmul_rn(pb, pb));
#pragma unroll
        for (int i = 0; i < 8; ++i) {
            const float cross = __fadd_rn(__fadd_rn(__fmul_rn(r[i], pr),
                                                    __fmul_rn(g[i], pg)),
                                          __fmul_rn(bl[i], pb));
            const float d2 = __fadd_rn(__fsub_rn(x2[i], __fmul_rn(2.0f, cross)),
                                       p2);
            if (d2 < best[i]) { best[i] = d2; bestk[i] = k; }  // strict <
        }
    }

    float orr[8], ogg[8], obb[8];
#pragma unroll
    for (int i = 0; i < 8; ++i) {
        orr[i] = spal[3 * bestk[i] + 0];
        ogg[i] = spal[3 * bestk[i] + 1];
        obb[i] = spal[3 * bestk[i] + 2];
    }

    float* ob = out + (size_t)b * 3 * HW + pix;
    *reinterpret_cast<float4*>(ob)              = make_float4(orr[0], orr[1], orr[2], orr[3]);
    *reinterpret_cast<float4*>(ob + 4)          = make_float4(orr[4], orr[5], orr[6], orr[7]);
    *reinterpret_cast<float4*>(ob + HW)         = make_float4(ogg[0], ogg[1], ogg[2], ogg[3]);
    *reinterpret_cast<float4*>(ob + HW + 4)     = make_float4(ogg[4], ogg[5], ogg[6], ogg[7]);
    *reinterpret_cast<float4*>(ob + 2 * HW)     = make_float4(obb[0], obb[1], obb[2], obb[3]);
    *reinterpret_cast<float4*>(ob + 2 * HW + 4) = make_float4(obb[4], obb[5], obb[6], obb[7]);
}

extern "C" void kernel_launch(void* const* d_in, const int* in_sizes, int n_in,
                              void* d_out, int out_size, void* d_ws, size_t ws_size,
                              hipStream_t stream) {
    const float* x   = (const float*)d_in[0];
    const float* pal = (const float*)d_in[1];
    float* out       = (float*)d_out;

    const int threads = 256;
    const long total_threads = NPIX / PPT;              // 524,288
    const int blocks = (int)(total_threads / threads);  // 2048
    color_reduce_kernel<<<blocks, threads, 0, stream>>>(x, pal, out);
}